// Round 1
// 716.892 us; speedup vs baseline: 1.0173x; 1.0173x over previous
//
#include <hip/hip_runtime.h>
#include <hip/hip_bf16.h>

// TransformerLayer (Swin shifted-window attention + MLP), fp32 I/O, MI355X.
// R8: fused flash attention. QBLK=128 per block (512 thr, 8 waves 4Mx2N),
// per-64-key tile: stage K[64x256]+V^T[256x64]+mask[128x64] via
// global_load_lds with XOR-granule swizzle (pre-swizzled global source,
// swizzled LDS reads); QK^T MFMA -> online softmax (cross-wave LDS reduce)
// -> P in LDS -> PV MFMA into regs; epilogue normalizes + de-windows +
// inverse-rolls into msg (d_out). Eliminates P global round-trip, the 2
// PV GEMM dispatches, and 4x of the K staging redundancy.
// Phases:
//  0. cvtw weights+mask->D ; cvt target->d_out.lo ; cvt source->d_out.hi
//  1. vw=QKV(tgt,Wv)->RB ; vwT=transpose->RC ; kw=QKV(tgt,Wk)->RB ; qw=QKV(src,Wq)->RA
//  2. flash_attn(qw,kw,vwT,mask16) -> msg (bf16, d_out)
//  3. msg@Wm^T->RB ; LN1->RC ; cvt source->RA(src16)
//  4. 4x slab: MLP1(src16|msg_ln,W1,gelu)->hid=d_out ; MLP2(hid,W2)->RB
//  5. LN2(RB)+source(fp32) -> d_out fp32

using bf16 = __hip_bfloat16;
typedef __attribute__((ext_vector_type(8))) short short8;
typedef __attribute__((ext_vector_type(4))) float f32x4;

__device__ __forceinline__ float bf2f(unsigned short b) {
    return __uint_as_float(((unsigned)b) << 16);
}
__device__ __forceinline__ unsigned short f2bf(float f) {
    unsigned u = __float_as_uint(f);
    unsigned r = (u + 0x7FFFu + ((u >> 16) & 1u)) >> 16;
    return (unsigned short)r;
}
__device__ __forceinline__ void cp16(const void* g, void* l) {
    __builtin_amdgcn_global_load_lds((const __attribute__((address_space(1))) void*)g,
                                     (__attribute__((address_space(3))) void*)l,
                                     16, 0, 0);
}
__device__ __forceinline__ float fast_gelu(float v) {
    const float z = v * (0.7978845608028654f + 0.0356774081f * v * v);
    const float t = 1.f - 2.f / (__expf(2.f * z) + 1.f);
    return 0.5f * v * (1.f + t);
}

constexpr int MODE_PLAIN = 0;
constexpr int MODE_QKV   = 1;  // store bf16 at roll(-16)+window-permuted row
constexpr int MODE_GELU  = 3;  // fast gelu then bf16 store

// C[M,N] = A[M,K] @ B[N,K]^T ; bf16 operands, fp32 acc. m97 structure.
template<int MODE, bool CONCAT>
__global__ __launch_bounds__(256)
void gemm_bt(const bf16* __restrict__ A, const bf16* __restrict__ A2,
             const bf16* __restrict__ Bm, void* __restrict__ C,
             int K, int ldc, long sAz, long sBz, int wbase)
{
    __shared__ __align__(16) bf16 As[128 * 32];
    __shared__ __align__(16) bf16 Bs[128 * 32];

    const int z = blockIdx.z;
    A  += (long)z * sAz;
    Bm += (long)z * sBz;

    const int tid  = threadIdx.x;
    const int wave = tid >> 6, lane = tid & 63;
    const int wm = wave >> 1, wn = wave & 1;
    const int quad = lane >> 4, lrow = lane & 15;
    const int m0 = blockIdx.x * 128, n0 = blockIdx.y * 128;

    f32x4 acc[4][4];
#pragma unroll
    for (int i = 0; i < 4; i++)
#pragma unroll
        for (int j = 0; j < 4; j++) acc[i][j] = (f32x4){0.f, 0.f, 0.f, 0.f};

    for (int k0 = 0; k0 < K; k0 += 32) {
#pragma unroll
        for (int inst = 0; inst < 2; ++inst) {
            const int chunk = wave * 2 + inst;
            const int u   = chunk * 64 + lane;
            const int row = u >> 2;
            const int kk  = (u & 3) << 3;
            const bf16* ga;
            if (CONCAT) {
                ga = (k0 < 256) ? (A  + (long)(m0 + row) * 256 + (k0 + kk))
                                : (A2 + (long)(m0 + row) * 256 + (k0 - 256 + kk));
            } else {
                ga = A + (long)(m0 + row) * K + (k0 + kk);
            }
            cp16(ga, As + chunk * 512);
            const bf16* gb = Bm + (long)(n0 + row) * K + (k0 + kk);
            cp16(gb, Bs + chunk * 512);
        }
        __syncthreads();

        short8 af[4], bfv[4];
#pragma unroll
        for (int i = 0; i < 4; i++) {
            af[i]  = *(const short8*)(As + (wm * 64 + i * 16 + lrow) * 32 + quad * 8);
            bfv[i] = *(const short8*)(Bs + (wn * 64 + i * 16 + lrow) * 32 + quad * 8);
        }
#pragma unroll
        for (int i = 0; i < 4; i++)
#pragma unroll
            for (int j = 0; j < 4; j++)
                acc[i][j] = __builtin_amdgcn_mfma_f32_16x16x32_bf16(
                    af[i], bfv[j], acc[i][j], 0, 0, 0);
        __syncthreads();
    }

    // C/D layout: col = lane&15, row = quad*4 + reg (m89/m91 verified)
    unsigned short* outb = (unsigned short*)C;
    if (MODE == MODE_QKV) {
#pragma unroll
        for (int i = 0; i < 4; i++)
#pragma unroll
            for (int j = 0; j < 4; j++)
#pragma unroll
                for (int r = 0; r < 4; r++) {
                    const int gm = m0 + wm * 64 + i * 16 + quad * 4 + r;
                    const int gn = n0 + wn * 64 + j * 16 + lrow;
                    const int batch = gm >> 12, pos = gm & 4095;
                    const int ii = pos >> 6, jj = pos & 63;
                    const int ri = (ii + 48) & 63, rj = (jj + 48) & 63; // roll(-16)
                    const long prow =
                        ((long)((batch << 2) + ((ri >> 5) << 1) + (rj >> 5)) << 10)
                        + ((ri & 31) << 5) + (rj & 31);
                    outb[prow * 256 + gn] = f2bf(acc[i][j][r]);
                }
    } else {
#pragma unroll
        for (int i = 0; i < 4; i++)
#pragma unroll
            for (int j = 0; j < 4; j++)
#pragma unroll
                for (int r = 0; r < 4; r++) {
                    const int gm = m0 + wm * 64 + i * 16 + quad * 4 + r;
                    const int gn = n0 + wn * 64 + j * 16 + lrow;
                    float v = acc[i][j][r];
                    if (MODE == MODE_GELU) v = fast_gelu(v);
                    outb[(long)gm * ldc + gn] = f2bf(v);
                }
    }
}

// Fused flash attention over one window (1024 keys), QBLK=128 query rows.
// 512 threads = 8 waves arranged 4(M) x 2(N). Per 64-key tile:
//   stage K[64x256] (32KB) + V^T[256x64] (32KB) + mask[128x64] (16KB, into
//   the P buffer) via cp16 with XOR-granule swizzle on the *global* source
//   (LDS dest linear, per m104/m173);
//   QK^T (32 MFMA/wave) -> scale+mask -> online softmax (row-max/sum via
//   lrow-shfl + cross-wn LDS reduce) -> P (bf16) written swizzled into the
//   mask buffer -> PV (32 MFMA/wave) accumulating O[128x256] in regs.
// Epilogue: O/l, de-window + inverse-roll (same math as old MODE_PV).
__global__ __launch_bounds__(512)
void flash_attn(const bf16* __restrict__ Q, const bf16* __restrict__ Kw,
                const bf16* __restrict__ VT, const bf16* __restrict__ mask16,
                bf16* __restrict__ msg)
{
    __shared__ __align__(16) bf16 Ks[64 * 256];            // 32 KB, [key][c] swz
    __shared__ __align__(16) bf16 Vs[256 * 64];            // 32 KB, [ch][k] swz
    __shared__ __align__(16) unsigned short Pm[128 * 64];  // 16 KB, mask then P
    __shared__ float redm[8][32], redl[8][32];

    // block remap: XCD c (= f&7) gets windows {c, 8+c, 16+c, 24+c} -> one
    // mask type per XCD, all 8 q-blocks of a window co-resident on one XCD.
    const int f   = blockIdx.x;
    const int win = (f & 7) + ((f >> 6) << 3);
    const int qb  = (f >> 3) & 7;
    const int m0  = qb << 7;

    const bf16* Qp = Q  + ((long)win << 18);
    const bf16* Kp = Kw + ((long)win << 18);
    const bf16* Vp = VT + ((long)win << 18);
    const bf16* mk = mask16 + ((long)(win & 3) << 20);

    const int tid  = threadIdx.x;
    const int wave = tid >> 6, lane = tid & 63;
    const int wm = wave >> 1, wn = wave & 1;
    const int quad = lane >> 4, lrow = lane & 15;

    // Q A-frags in registers: rows m0 + wm*32 + mf*16 + lrow, once per block.
    short8 qf[2][8];
#pragma unroll
    for (int mf = 0; mf < 2; ++mf) {
        const bf16* qr = Qp + (long)(m0 + (wm << 5) + (mf << 4) + lrow) * 256 + quad * 8;
#pragma unroll
        for (int kc = 0; kc < 8; ++kc)
            qf[mf][kc] = *(const short8*)(qr + kc * 32);
    }

    f32x4 o[2][8];
#pragma unroll
    for (int mf = 0; mf < 2; ++mf)
#pragma unroll
        for (int nf = 0; nf < 8; ++nf) o[mf][nf] = (f32x4){0.f, 0.f, 0.f, 0.f};
    float m_run[2][4], l_run[2][4];
#pragma unroll
    for (int mf = 0; mf < 2; ++mf)
#pragma unroll
        for (int r = 0; r < 4; ++r) { m_run[mf][r] = -3.4e38f; l_run[mf][r] = 0.f; }

    for (int kt = 0; kt < 16; ++kt) {
        // ---- stage: K chunks 0..31, V chunks 32..63, mask chunks 64..79 ----
#pragma unroll
        for (int i = 0; i < 10; ++i) {
            const int ch = wave * 10 + i;
            if (ch < 32) {
                const int u = (ch << 6) + lane;
                const int key = u >> 5, g = u & 31;
                const int sg = (g & 24) | ((g ^ key) & 7);
                cp16(Kp + (long)((kt << 6) + key) * 256 + (sg << 3), Ks + (ch << 9));
            } else if (ch < 64) {
                const int u = ((ch - 32) << 6) + lane;
                const int vc = u >> 3, g = u & 7;
                cp16(Vp + ((long)vc << 10) + (kt << 6) + ((g ^ (vc & 7)) << 3),
                     Vs + ((ch - 32) << 9));
            } else {
                const int u = ((ch - 64) << 6) + lane;
                const int row = u >> 3, g = u & 7;
                cp16(mk + (long)(m0 + row) * 1024 + (kt << 6) + ((g ^ (row & 7)) << 3),
                     Pm + ((ch - 64) << 9));
            }
        }
        __syncthreads();

        // ---- QK^T: s[mf][nf], rows 32*wm+16*mf, keys 32*wn+16*nf ----
        f32x4 s[2][2];
#pragma unroll
        for (int mf = 0; mf < 2; ++mf)
#pragma unroll
            for (int nf = 0; nf < 2; ++nf) s[mf][nf] = (f32x4){0.f, 0.f, 0.f, 0.f};
#pragma unroll
        for (int kc = 0; kc < 8; ++kc)
#pragma unroll
            for (int nf = 0; nf < 2; ++nf) {
                const int key = (wn << 5) + (nf << 4) + lrow;
                const int g = (kc << 2) + quad;
                const int sg = (g & 24) | ((g ^ key) & 7);
                const short8 bfv = *(const short8*)(Ks + (key << 8) + (sg << 3));
                s[0][nf] = __builtin_amdgcn_mfma_f32_16x16x32_bf16(qf[0][kc], bfv, s[0][nf], 0, 0, 0);
                s[1][nf] = __builtin_amdgcn_mfma_f32_16x16x32_bf16(qf[1][kc], bfv, s[1][nf], 0, 0, 0);
            }

        // ---- scale + mask + partial row-max ----
        float vmax[2][4];
#pragma unroll
        for (int mf = 0; mf < 2; ++mf)
#pragma unroll
            for (int r = 0; r < 4; ++r) {
                const int row = (wm << 5) + (mf << 4) + (quad << 2) + r;
                const int rb = row << 6;
                const int rx = (row & 7) << 3;
#pragma unroll
                for (int nf = 0; nf < 2; ++nf) {
                    const int k = (wn << 5) + (nf << 4) + lrow;
                    s[mf][nf][r] = s[mf][nf][r] * 0.0625f
                                 + bf2f(Pm[rb + (((k >> 3) << 3) ^ rx) + (k & 7)]);
                }
                float v = fmaxf(s[mf][0][r], s[mf][1][r]);
#pragma unroll
                for (int off = 1; off < 16; off <<= 1) v = fmaxf(v, __shfl_xor(v, off, 64));
                vmax[mf][r] = v;
            }
        if (lrow == 0) {
#pragma unroll
            for (int mf = 0; mf < 2; ++mf)
#pragma unroll
                for (int r = 0; r < 4; ++r)
                    redm[wave][(mf << 4) + (quad << 2) + r] = vmax[mf][r];
        }
        __syncthreads();

        // ---- combine max, exp, P->LDS (over the consumed mask), rescale O ----
        float fac[2][4], ps[2][4];
#pragma unroll
        for (int mf = 0; mf < 2; ++mf)
#pragma unroll
            for (int r = 0; r < 4; ++r) {
                const int r32 = (mf << 4) + (quad << 2) + r;
                const float mn = fmaxf(m_run[mf][r],
                                 fmaxf(redm[wm << 1][r32], redm[(wm << 1) + 1][r32]));
                fac[mf][r] = __expf(m_run[mf][r] - mn);
                m_run[mf][r] = mn;
                ps[mf][r] = 0.f;
            }
#pragma unroll
        for (int mf = 0; mf < 2; ++mf)
#pragma unroll
            for (int r = 0; r < 4; ++r) {
                const int row = (wm << 5) + (mf << 4) + (quad << 2) + r;
                const int rb = row << 6;
                const int rx = (row & 7) << 3;
#pragma unroll
                for (int nf = 0; nf < 2; ++nf) {
                    const int k = (wn << 5) + (nf << 4) + lrow;
                    const float e = __expf(s[mf][nf][r] - m_run[mf][r]);
                    ps[mf][r] += e;
                    Pm[rb + (((k >> 3) << 3) ^ rx) + (k & 7)] = f2bf(e);
                }
            }
#pragma unroll
        for (int mf = 0; mf < 2; ++mf)
#pragma unroll
            for (int r = 0; r < 4; ++r) {
                float v = ps[mf][r];
#pragma unroll
                for (int off = 1; off < 16; off <<= 1) v += __shfl_xor(v, off, 64);
                ps[mf][r] = v;
#pragma unroll
                for (int nf = 0; nf < 8; ++nf) o[mf][nf][r] *= fac[mf][r];
            }
        if (lrow == 0) {
#pragma unroll
            for (int mf = 0; mf < 2; ++mf)
#pragma unroll
                for (int r = 0; r < 4; ++r)
                    redl[wave][(mf << 4) + (quad << 2) + r] = ps[mf][r];
        }
        __syncthreads();

#pragma unroll
        for (int mf = 0; mf < 2; ++mf)
#pragma unroll
            for (int r = 0; r < 4; ++r) {
                const int r32 = (mf << 4) + (quad << 2) + r;
                l_run[mf][r] = l_run[mf][r] * fac[mf][r]
                             + redl[wm << 1][r32] + redl[(wm << 1) + 1][r32];
            }

        // ---- PV: O[128x256] += P[128x64] @ V[64x256] ----
#pragma unroll
        for (int ks = 0; ks < 2; ++ks) {
            short8 af[2];
#pragma unroll
            for (int mf = 0; mf < 2; ++mf) {
                const int rA = (wm << 5) + (mf << 4) + lrow;
                const int g = (ks << 2) + quad;
                af[mf] = *(const short8*)((const unsigned short*)Pm
                             + (rA << 6) + ((g ^ (rA & 7)) << 3));
            }
#pragma unroll
            for (int nf = 0; nf < 8; ++nf) {
                const int vc = (wn << 7) + (nf << 4) + lrow;
                const int g = (ks << 2) + quad;
                const short8 bfv = *(const short8*)(Vs + (vc << 6) + ((g ^ (vc & 7)) << 3));
                o[0][nf] = __builtin_amdgcn_mfma_f32_16x16x32_bf16(af[0], bfv, o[0][nf], 0, 0, 0);
                o[1][nf] = __builtin_amdgcn_mfma_f32_16x16x32_bf16(af[1], bfv, o[1][nf], 0, 0, 0);
            }
        }
        __syncthreads();
    }

    // ---- epilogue: normalize, de-window + inverse-roll (old MODE_PV math) ----
    const int batch = win >> 2;
    const int s1 = (win >> 1) & 1, s2 = win & 1;
    unsigned short* outb = (unsigned short*)msg;
#pragma unroll
    for (int mf = 0; mf < 2; ++mf)
#pragma unroll
        for (int r = 0; r < 4; ++r) {
            const float inv = 1.f / l_run[mf][r];
            const int gm = m0 + (wm << 5) + (mf << 4) + (quad << 2) + r;
            const int r5 = gm >> 5, c5 = gm & 31;
            const int ii = ((s1 << 5) + r5 + 16) & 63;
            const int jj = ((s2 << 5) + c5 + 16) & 63;
            const long mr = (long)batch * 4096 + ii * 64 + jj;
#pragma unroll
            for (int nf = 0; nf < 8; ++nf) {
                const int gn = (wn << 7) + (nf << 4) + lrow;
                outb[mr * 256 + gn] = f2bf(o[mf][nf][r] * inv);
            }
        }
}

// merged conversion: 6 weights + mask, segments by blockIdx.y
__global__ __launch_bounds__(256)
void cvtw_k(const float* __restrict__ w0, const float* __restrict__ w1,
            const float* __restrict__ w2, const float* __restrict__ w3,
            const float* __restrict__ w4, const float* __restrict__ w5,
            const float* __restrict__ w6, unsigned short* __restrict__ d)
{
    const float* s; long n4, off4;
    switch (blockIdx.y) {
    case 0:  s = w0; n4 = 16384;   off4 = 0;      break;
    case 1:  s = w1; n4 = 16384;   off4 = 16384;  break;
    case 2:  s = w2; n4 = 16384;   off4 = 32768;  break;
    case 3:  s = w3; n4 = 16384;   off4 = 49152;  break;
    case 4:  s = w4; n4 = 262144;  off4 = 65536;  break;
    case 5:  s = w5; n4 = 131072;  off4 = 327680; break;
    default: s = w6; n4 = 1048576; off4 = 458752; break;  // mask
    }
    ushort4* dst = (ushort4*)d + off4;
    for (long i = (long)blockIdx.x * 256 + threadIdx.x; i < n4;
         i += (long)gridDim.x * 256) {
        const float4 v = ((const float4*)s)[i];
        ushort4 o;
        o.x = f2bf(v.x); o.y = f2bf(v.y); o.z = f2bf(v.z); o.w = f2bf(v.w);
        dst[i] = o;
    }
}

__global__ __launch_bounds__(256)
void cvt_k(const float* __restrict__ s, unsigned short* __restrict__ d, long n4)
{
    for (long i = (long)blockIdx.x * 256 + threadIdx.x; i < n4;
         i += (long)gridDim.x * 256) {
        const float4 v = ((const float4*)s)[i];
        ushort4 o;
        o.x = f2bf(v.x); o.y = f2bf(v.y); o.z = f2bf(v.z); o.w = f2bf(v.w);
        ((ushort4*)d)[i] = o;
    }
}

// vwT[win][c][s] = vw[win][s][c], 64x64 LDS tiles
__global__ __launch_bounds__(256)
void transpose_vw(const bf16* __restrict__ vw, bf16* __restrict__ vwT)
{
    __shared__ bf16 t[64][65];
    const int win = blockIdx.z;
    const int s0 = blockIdx.x * 64, c0 = blockIdx.y * 64;
    const bf16* src = vw  + ((long)win << 18);
    bf16*       dst = vwT + ((long)win << 18);
    const int tid = threadIdx.x;
#pragma unroll
    for (int ii = 0; ii < 16; ++ii) {
        const int lin = ii * 256 + tid;
        const int r = lin >> 6, c = lin & 63;
        t[r][c] = src[(long)(s0 + r) * 256 + c0 + c];
    }
    __syncthreads();
#pragma unroll
    for (int ii = 0; ii < 16; ++ii) {
        const int lin = ii * 256 + tid;
        const int r = lin >> 6, c = lin & 63;
        dst[(long)(c0 + r) * 1024 + s0 + c] = t[c][r];
    }
}

// LN1: bf16 in -> bf16 out, fp32 gamma/beta. One 256-ch row per wave.
__global__ __launch_bounds__(256)
void ln1_k(const bf16* __restrict__ x, const float* __restrict__ g,
           const float* __restrict__ be, bf16* __restrict__ out)
{
    const int wave = threadIdx.x >> 6, lane = threadIdx.x & 63;
    const long row = (long)blockIdx.x * 4 + wave;
    const ushort4 u = ((const ushort4*)((const unsigned short*)x + (row << 8)))[lane];
    const float v0 = bf2f(u.x), v1 = bf2f(u.y), v2 = bf2f(u.z), v3 = bf2f(u.w);
    float s = v0 + v1 + v2 + v3;
    float q = v0 * v0 + v1 * v1 + v2 * v2 + v3 * v3;
#pragma unroll
    for (int o = 1; o < 64; o <<= 1) { s += __shfl_xor(s, o, 64); q += __shfl_xor(q, o, 64); }
    const float mean = s * 0.00390625f;
    const float var  = q * 0.00390625f - mean * mean;
    const float inv  = rsqrtf(fmaxf(var, 0.f) + 1e-5f);
    const float4 gg = ((const float4*)g)[lane];
    const float4 bb = ((const float4*)be)[lane];
    ushort4 o4;
    o4.x = f2bf((v0 - mean) * inv * gg.x + bb.x);
    o4.y = f2bf((v1 - mean) * inv * gg.y + bb.y);
    o4.z = f2bf((v2 - mean) * inv * gg.z + bb.z);
    o4.w = f2bf((v3 - mean) * inv * gg.w + bb.w);
    ((ushort4*)((unsigned short*)out + (row << 8)))[lane] = o4;
}

// LN2 + residual: bf16 in, fp32 gamma/beta/residual, fp32 out.
__global__ __launch_bounds__(256)
void ln2_k(const bf16* __restrict__ x, const float* __restrict__ g,
           const float* __restrict__ be, const float* __restrict__ res,
           float* __restrict__ out)
{
    const int wave = threadIdx.x >> 6, lane = threadIdx.x & 63;
    const long row = (long)blockIdx.x * 4 + wave;
    const ushort4 u = ((const ushort4*)((const unsigned short*)x + (row << 8)))[lane];
    const float v0 = bf2f(u.x), v1 = bf2f(u.y), v2 = bf2f(u.z), v3 = bf2f(u.w);
    float s = v0 + v1 + v2 + v3;
    float q = v0 * v0 + v1 * v1 + v2 * v2 + v3 * v3;
#pragma unroll
    for (int o = 1; o < 64; o <<= 1) { s += __shfl_xor(s, o, 64); q += __shfl_xor(q, o, 64); }
    const float mean = s * 0.00390625f;
    const float var  = q * 0.00390625f - mean * mean;
    const float inv  = rsqrtf(fmaxf(var, 0.f) + 1e-5f);
    const float4 gg = ((const float4*)g)[lane];
    const float4 bb = ((const float4*)be)[lane];
    const float4 rr = ((const float4*)(res + (row << 8)))[lane];
    float4 o4;
    o4.x = (v0 - mean) * inv * gg.x + bb.x + rr.x;
    o4.y = (v1 - mean) * inv * gg.y + bb.y + rr.y;
    o4.z = (v2 - mean) * inv * gg.z + bb.z + rr.z;
    o4.w = (v3 - mean) * inv * gg.w + bb.w + rr.w;
    ((float4*)(out + (row << 8)))[lane] = o4;
}

extern "C" void kernel_launch(void* const* d_in, const int* in_sizes, int n_in,
                              void* d_out, int out_size, void* d_ws, size_t ws_size,
                              hipStream_t stream)
{
    const float* source = (const float*)d_in[0];
    const float* target = (const float*)d_in[1];
    const float* mask   = (const float*)d_in[2];
    const float* Wq = (const float*)d_in[3];
    const float* Wk = (const float*)d_in[4];
    const float* Wv = (const float*)d_in[5];
    const float* Wm = (const float*)d_in[6];
    const float* ln1g = (const float*)d_in[7];
    const float* ln1b = (const float*)d_in[8];
    const float* W1 = (const float*)d_in[9];
    const float* W2 = (const float*)d_in[10];
    const float* ln2g = (const float*)d_in[11];
    const float* ln2b = (const float*)d_in[12];
    float* out = (float*)d_out;

    char* ws = (char*)d_ws;
    const size_t MB = 1ull << 20;

    bf16* RA = (bf16*)(ws +  0 * MB);   // qw -> src16
    bf16* RB = (bf16*)(ws + 16 * MB);   // vw -> kw -> msg_mm -> mlp_out
    bf16* RC = (bf16*)(ws + 32 * MB);   // vwT -> msg_ln
    unsigned short* D = (unsigned short*)(ws + 48 * MB);  // weights+mask bf16
    bf16* Wq16 = (bf16*)(D);
    bf16* Wk16 = (bf16*)(D + 65536);
    bf16* Wv16 = (bf16*)(D + 131072);
    bf16* Wm16 = (bf16*)(D + 196608);
    bf16* W116 = (bf16*)(D + 262144);
    bf16* W216 = (bf16*)(D + 1310720);
    bf16* mask16 = (bf16*)(D + 1835008);
    // d_out (33.55 MB) phased scratch:
    bf16* tgt16 = (bf16*)d_out;                       // [0, 16.78 MB)
    bf16* src16 = (bf16*)((char*)d_out + 16777216);   // [16.78, 33.55 MB)
    bf16* msgb  = (bf16*)d_out;                       // flash output (16.78 MB)
    bf16* hid   = (bf16*)d_out;                       // MLP slab hidden

    // 0) weights + mask + activations -> bf16
    cvtw_k<<<dim3(256, 7), 256, 0, stream>>>(Wq, Wk, Wv, Wm, W1, W2, mask, D);
    cvt_k<<<4096, 256, 0, stream>>>(target, (unsigned short*)tgt16, 2097152);
    cvt_k<<<4096, 256, 0, stream>>>(source, (unsigned short*)src16, 2097152);

    // 1) projections (roll+window-permuted store) + V transpose
    gemm_bt<MODE_QKV, false><<<dim3(256, 2, 1), 256, 0, stream>>>(
        tgt16, nullptr, Wv16, RB, 256, 256, 0, 0, 0);
    transpose_vw<<<dim3(16, 4, 32), 256, 0, stream>>>(RB, RC);
    gemm_bt<MODE_QKV, false><<<dim3(256, 2, 1), 256, 0, stream>>>(
        tgt16, nullptr, Wk16, RB, 256, 256, 0, 0, 0);
    gemm_bt<MODE_QKV, false><<<dim3(256, 2, 1), 256, 0, stream>>>(
        src16, nullptr, Wq16, RA, 256, 256, 0, 0, 0);

    // 2) fused flash attention: all 32 windows, msg -> d_out (bf16)
    flash_attn<<<dim3(256), 512, 0, stream>>>(RA, RB, RC, mask16, msgb);

    // 3) msg @ Wm^T -> RB ; LN1 -> RC ; re-convert source -> RA
    gemm_bt<MODE_PLAIN, false><<<dim3(256, 2, 1), 256, 0, stream>>>(
        msgb, nullptr, Wm16, RB, 256, 256, 0, 0, 0);
    ln1_k<<<8192, 256, 0, stream>>>(RB, ln1g, ln1b, RC);
    cvt_k<<<8192, 256, 0, stream>>>(source, (unsigned short*)RA, 2097152);

    // 4) MLP, 4 slabs of 8192 rows (hid = full d_out, out -> RB)
    for (int sl = 0; sl < 4; ++sl) {
        const long ro = (long)sl * 8192 * 256;
        gemm_bt<MODE_GELU, true><<<dim3(64, 16, 1), 256, 0, stream>>>(
            RA + ro, RC + ro, W116, hid, 512, 2048, 0, 0, 0);
        gemm_bt<MODE_PLAIN, false><<<dim3(64, 2, 1), 256, 0, stream>>>(
            hid, nullptr, W216, RB + ro, 2048, 256, 0, 0, 0);
    }

    // 5) LN2 + fp32 residual -> d_out
    ln2_k<<<8192, 256, 0, stream>>>(RB, ln2g, ln2b, source, out);
}